// Round 3
// baseline (1586.265 us; speedup 1.0000x reference)
//
#include <hip/hip_runtime.h>
#include <cstdint>
#include <cstddef>

// ---------------- types ----------------
typedef __attribute__((ext_vector_type(8))) __bf16 bf16x8;   // MFMA A/B frag (4 VGPRs)
typedef __attribute__((ext_vector_type(4))) float  f32x4;    // MFMA C/D frag

__device__ __forceinline__ unsigned short f2bf(float f) {
  unsigned u = __float_as_uint(f);
  u += 0x7FFFu + ((u >> 16) & 1u);   // round-to-nearest-even
  return (unsigned short)(u >> 16);
}

// async global->LDS, 16B per lane; LDS dest is wave-uniform base + lane*16
__device__ __forceinline__ void gl_lds16(const void* g, void* l) {
  __builtin_amdgcn_global_load_lds(
      (const __attribute__((address_space(1))) char*)g,
      (__attribute__((address_space(3))) char*)l, 16, 0, 0);
}

__device__ __forceinline__ float sigm(float x) { return 1.f / (1.f + __expf(-x)); }
__device__ __forceinline__ float ftanh(float x) {
  x = fminf(15.f, fmaxf(-15.f, x));
  float e = __expf(2.f * x);
  return (e - 1.f) / (e + 1.f);
}

// ---------------- sort + meta outputs + gathers (1 block) ----------------
__global__ __launch_bounds__(256) void k_sort(
    const float* __restrict__ img, const int* __restrict__ caps,
    const int* __restrict__ clen,
    float* __restrict__ out_caps, float* __restrict__ out_dl, float* __restrict__ out_si,
    int* __restrict__ ws_caps, int* __restrict__ ws_dl,
    unsigned short* __restrict__ h0,
    int* __restrict__ bar)
{
  __shared__ int len_s[64], si_s[64], dl_s[64];
  const int tid = threadIdx.x;
  if (tid == 0) bar[0] = 0;          // grid-barrier counter for lstm_persist
  if (tid < 64) len_s[tid] = clen[tid];
  __syncthreads();
  if (tid < 64) {
    int li = len_s[tid], r = 0;
    for (int j = 0; j < 64; j++) {
      int lj = len_s[j];
      if (lj > li || (lj == li && j < tid)) r++;   // stable descending rank
    }
    si_s[r] = tid;
    dl_s[r] = li - 1;
  }
  __syncthreads();
  if (tid < 64) {
    out_si[tid] = (float)si_s[tid];
    out_dl[tid] = (float)dl_s[tid];
    ws_dl[tid] = dl_s[tid];
  }
  for (int i = tid; i < 64 * 52; i += 256) {
    int p = i / 52, t = i - p * 52;
    int v = caps[si_s[p] * 52 + t];
    out_caps[i] = (float)v;
    ws_caps[i] = v;
  }
  for (int i = tid; i < 64 * 512; i += 256) {
    int b = i >> 9, k = i & 511;
    h0[i] = f2bf(img[si_s[b] * 512 + k]);
  }
}

// ---------------- fp32 -> bf16 cast (vectorized x4) ----------------
__global__ void k_cast(const float* __restrict__ s, unsigned short* __restrict__ d, int n4) {
  int i = blockIdx.x * blockDim.x + threadIdx.x;
  if (i < n4) {
    float4 v = ((const float4*)s)[i];
    ushort4 o;
    o.x = f2bf(v.x); o.y = f2bf(v.y); o.z = f2bf(v.z); o.w = f2bf(v.w);
    ((ushort4*)d)[i] = o;
  }
}

// ---------------- embedding gather -> bf16 A matrix [3264][512] ----------------
__global__ __launch_bounds__(256) void k_gather(
    const float* __restrict__ embW, const int* __restrict__ ws_caps,
    unsigned short* __restrict__ A)
{
  int m = blockIdx.x;                 // 0..3263, m = b*51 + t
  int b = m / 51, t = m - b * 51;
  int tok = ws_caps[b * 52 + t];
  const float* src = embW + (size_t)tok * 512;
  unsigned short* dst = A + (size_t)m * 512;
  for (int k = threadIdx.x; k < 512; k += 256) dst[k] = f2bf(src[k]);
}

// ---------------- 128x128 MFMA GEMM, BK=64, XOR-swizzled LDS ----------------
// C = A(MxK) @ Bt(NxK)^T, K=512
// EPI 0: out = acc + bias1[col] + bias2[col]          (Xpre)
// EPI 1: out = (t < dl[b]) ? acc + bias1[col] : 0     (predictions; row = b*51+t)
template <int EPI>
__global__ __launch_bounds__(256) void gemm_bt(
    const unsigned short* __restrict__ A, const unsigned short* __restrict__ Bt,
    float* __restrict__ out, int M, int N,
    const float* __restrict__ bias1, const float* __restrict__ bias2,
    const int* __restrict__ dl, int per_xcd)
{
  constexpr int K = 512;
  constexpr int BK = 64;
  __shared__ unsigned short smA[128 * BK];   // 16 KB
  __shared__ unsigned short smB[128 * BK];   // 16 KB
  const int mtiles = (M + 127) >> 7;
  const int total = mtiles * ((N + 127) >> 7);
  int tile = (blockIdx.x & 7) * per_xcd + (blockIdx.x >> 3);
  if (tile >= total) return;
  const int bm = tile % mtiles;
  const int bn = tile / mtiles;
  const int wave = threadIdx.x >> 6;
  const int lane = threadIdx.x & 63;
  const int crow = lane >> 3;                // row within 8-row 1KB chunk
  const int cu   = lane & 7;                 // 16B unit within 128B row
  const int wr = (wave >> 1) * 64;
  const int wc = (wave & 1) * 64;
  const int rsel = lane & 15;
  const int ko = (lane >> 4) * 8;            // 0,8,16,24
  const unsigned short* Ab = A + (size_t)bm * 128 * K;
  const unsigned short* Bb = Bt + (size_t)bn * 128 * K;
  f32x4 acc[4][4] = {};
  for (int k0 = 0; k0 < K; k0 += BK) {
#pragma unroll
    for (int cc = 0; cc < 4; cc++) {
      int chunk = wave * 4 + cc;
      int row = chunk * 8 + crow;
      int gu = cu ^ (row & 7);               // global 16B-unit (swizzle source)
      gl_lds16(Ab + (size_t)row * K + k0 + gu * 8, (char*)smA + chunk * 1024);
      gl_lds16(Bb + (size_t)row * K + k0 + gu * 8, (char*)smB + chunk * 1024);
    }
    __syncthreads();
    bf16x8 af[2][4], bfr[2][4];
#pragma unroll
    for (int kh = 0; kh < 2; kh++) {
      int u = kh * 4 + (ko >> 3);            // 16B unit index 0..7
#pragma unroll
      for (int mt = 0; mt < 4; mt++) {
        int row = wr + mt * 16 + rsel;
        af[kh][mt] = *(const bf16x8*)&smA[row * BK + ((u ^ (row & 7)) << 3)];
      }
#pragma unroll
      for (int nt = 0; nt < 4; nt++) {
        int row = wc + nt * 16 + rsel;
        bfr[kh][nt] = *(const bf16x8*)&smB[row * BK + ((u ^ (row & 7)) << 3)];
      }
    }
#pragma unroll
    for (int kh = 0; kh < 2; kh++)
#pragma unroll
      for (int mt = 0; mt < 4; mt++)
#pragma unroll
        for (int nt = 0; nt < 4; nt++)
          acc[mt][nt] = __builtin_amdgcn_mfma_f32_16x16x32_bf16(af[kh][mt], bfr[kh][nt], acc[mt][nt], 0, 0, 0);
    __syncthreads();
  }
  // epilogue: C mapping col=lane&15, row=(lane>>4)*4+reg
#pragma unroll
  for (int mt = 0; mt < 4; mt++) {
#pragma unroll
    for (int nt = 0; nt < 4; nt++) {
      int row0 = bm * 128 + wr + mt * 16 + (lane >> 4) * 4;
      int col = bn * 128 + wc + nt * 16 + (lane & 15);
      float b1 = bias1[col];
#pragma unroll
      for (int r = 0; r < 4; r++) {
        int row = row0 + r;
        if (row < M) {
          float v = acc[mt][nt][r];
          if (EPI == 0) {
            out[(size_t)row * N + col] = v + b1 + bias2[col];
          } else {
            int b = row / 51;
            int t = row - b * 51;
            out[(size_t)row * N + col] = (t < dl[b]) ? (v + b1) : 0.f;
          }
        }
      }
    }
  }
}

// ---------------- persistent fused LSTM: all 51 steps in one launch ----------
// 32 blocks x 512 threads; block g owns h-columns [16g,16g+16) for all 4 gates.
// Whh panel in registers (wf[16]); NO threadfences: the h exchange itself is
// coherent. h_out stores and h_in loads are agent-scope relaxed atomics
// (sc0 sc1 -> bypass L1/L2, served at the Infinity-Cache coherence point; the
// same path round-2's bar spin-load already proved visible cross-XCD).
// Ordering: __syncthreads drains each thread's coherent stores (compiler emits
// s_waitcnt vmcnt(0) before s_barrier) BEFORE tid0 publishes arrival, so by
// the time bar reaches the goal every h element is at the coherence point.
// This deletes the per-step buffer_wbl2 + whole-L1/L2 buffer_inv of the old
// __threadfence protocol, which the r1/r2 A/B showed costs ~10 us/step.
__global__ __launch_bounds__(512, 2) void lstm_persist(
    unsigned short* __restrict__ hc0,          // [64][512] bf16 (t even input)
    unsigned short* __restrict__ hc1,          // [64][512] bf16
    const unsigned short* __restrict__ Whh,    // [2048][512] bf16
    const float* __restrict__ Xpre,            // [3264][2048]
    unsigned short* __restrict__ Hall,         // [3328][512] bf16
    int* __restrict__ bar)
{
  __shared__ float smG[4][64][20];             // 20.5 KB gate exchange (pad 20)
  const int g = blockIdx.x;                    // 0..31
  const int tid = threadIdx.x;
  const int wave = tid >> 6;
  const int lane = tid & 63;
  const int wm = wave >> 2;                    // 0..1
  const int wn = wave & 3;                     // 0..3 (gate)
  const int rsel = lane & 15;
  const int quad = lane >> 4;

  // one-time: this wave's Whh panel -> registers.
  // B-frag for k-step ks: lane holds Bt[row = wn*512 + g*16 + rsel][ks*32 + quad*8 ..+8)
  bf16x8 wf[16];
  {
    const unsigned short* wsrc =
        Whh + (size_t)(wn * 512 + g * 16 + rsel) * 512 + quad * 8;
#pragma unroll
    for (int ks = 0; ks < 16; ks++)
      wf[ks] = *(const bf16x8*)(wsrc + ks * 32);
  }

  // per-thread element ownership (consistent across t): e0=(b0,jj), e1=(b1,jj)
  const int jj = tid & 15;
  const int b0 = tid >> 4;        // 0..31
  const int b1 = b0 + 32;         // 32..63
  float c0 = 0.f, c1 = 0.f;       // cell state in registers

  // Xpre for t=0 (prefetched; subsequent steps prefetch before the barrier wait)
  const float* x0base = Xpre + (size_t)(b0 * 51) * 2048 + g * 16 + jj;
  const float* x1base = Xpre + (size_t)(b1 * 51) * 2048 + g * 16 + jj;
  float xp0[4], xp1[4];
#pragma unroll
  for (int q = 0; q < 4; q++) { xp0[q] = x0base[q * 512]; xp1[q] = x1base[q * 512]; }

  typedef union { unsigned long long q[2]; bf16x8 v; } qv;

  for (int t = 0; t < 51; t++) {
    const unsigned short* h_in = (t & 1) ? hc1 : hc0;
    unsigned short* h_out      = (t & 1) ? hc0 : hc1;

    // A-fragments via coherence-point loads (bypass L1/L2 -> always fresh).
    // af[ks]: rows wm*32(+16) + rsel, bytes [ks*64 + quad*16, +16)
    qv af0[16], af1[16];
    {
      const unsigned short* a0s = h_in + (size_t)(wm * 32 + rsel) * 512 + quad * 8;
      const unsigned short* a1s = a0s + 16 * 512;
#pragma unroll
      for (int ks = 0; ks < 16; ks++) {
        af0[ks].q[0] = __hip_atomic_load((unsigned long long*)(a0s + ks * 32),
                                         __ATOMIC_RELAXED, __HIP_MEMORY_SCOPE_AGENT);
        af0[ks].q[1] = __hip_atomic_load((unsigned long long*)(a0s + ks * 32 + 4),
                                         __ATOMIC_RELAXED, __HIP_MEMORY_SCOPE_AGENT);
        af1[ks].q[0] = __hip_atomic_load((unsigned long long*)(a1s + ks * 32),
                                         __ATOMIC_RELAXED, __HIP_MEMORY_SCOPE_AGENT);
        af1[ks].q[1] = __hip_atomic_load((unsigned long long*)(a1s + ks * 32 + 4),
                                         __ATOMIC_RELAXED, __HIP_MEMORY_SCOPE_AGENT);
      }
    }

    // GEMM: block out = [64 batch][64 gate-cols], K=512, B from registers
    f32x4 acc0 = {}, acc1 = {};
#pragma unroll
    for (int ks = 0; ks < 16; ks++) {
      acc0 = __builtin_amdgcn_mfma_f32_16x16x32_bf16(af0[ks].v, wf[ks], acc0, 0, 0, 0);
      acc1 = __builtin_amdgcn_mfma_f32_16x16x32_bf16(af1[ks].v, wf[ks], acc1, 0, 0, 0);
    }

    // exchange through LDS: C mapping col=lane&15 -> gate-col, row=quad*4+r -> batch
#pragma unroll
    for (int r = 0; r < 4; r++) smG[wn][wm * 32 + quad * 4 + r][rsel] = acc0[r];
#pragma unroll
    for (int r = 0; r < 4; r++) smG[wn][wm * 32 + 16 + quad * 4 + r][rsel] = acc1[r];
    __syncthreads();

    // fused LSTM elementwise (2 elements/thread), c in registers.
    // h_out stores are coherence-point stores (visible to all XCDs once
    // vmcnt-drained, which the next __syncthreads enforces).
    {
      float iv = smG[0][b0][jj] + xp0[0];
      float fv = smG[1][b0][jj] + xp0[1];
      float gv = smG[2][b0][jj] + xp0[2];
      float ov = smG[3][b0][jj] + xp0[3];
      c0 = sigm(fv) * c0 + sigm(iv) * ftanh(gv);
      float hn = sigm(ov) * ftanh(c0);
      unsigned short hb = f2bf(hn);
      __hip_atomic_store(&h_out[(b0 << 9) + g * 16 + jj], hb,
                         __ATOMIC_RELAXED, __HIP_MEMORY_SCOPE_AGENT);
      Hall[(size_t)(b0 * 51 + t) * 512 + g * 16 + jj] = hb;
    }
    {
      float iv = smG[0][b1][jj] + xp1[0];
      float fv = smG[1][b1][jj] + xp1[1];
      float gv = smG[2][b1][jj] + xp1[2];
      float ov = smG[3][b1][jj] + xp1[3];
      c1 = sigm(fv) * c1 + sigm(iv) * ftanh(gv);
      float hn = sigm(ov) * ftanh(c1);
      unsigned short hb = f2bf(hn);
      __hip_atomic_store(&h_out[(b1 << 9) + g * 16 + jj], hb,
                         __ATOMIC_RELAXED, __HIP_MEMORY_SCOPE_AGENT);
      Hall[(size_t)(b1 * 51 + t) * 512 + g * 16 + jj] = hb;
    }

    // fence-free grid barrier (also re-opens smG for next step's writes)
    if (t != 50) {
      // prefetch next step's Xpre while we'd otherwise idle in the barrier
#pragma unroll
      for (int q = 0; q < 4; q++) {
        xp0[q] = x0base[(size_t)(t + 1) * 2048 + q * 512];
        xp1[q] = x1base[(size_t)(t + 1) * 2048 + q * 512];
      }
      __syncthreads();   // drains this block's coherent h stores (vmcnt 0)
      if (tid == 0) {
        __hip_atomic_fetch_add(bar, 1, __ATOMIC_RELAXED, __HIP_MEMORY_SCOPE_AGENT);
        int goal = 32 * (t + 1);
        while (__hip_atomic_load(bar, __ATOMIC_RELAXED, __HIP_MEMORY_SCOPE_AGENT) < goal)
          __builtin_amdgcn_s_sleep(2);
      }
      __syncthreads();
    }
  }
}

// ---------------- launch ----------------
extern "C" void kernel_launch(void* const* d_in, const int* in_sizes, int n_in,
                              void* d_out, int out_size, void* d_ws, size_t ws_size,
                              hipStream_t stream)
{
  const float* img  = (const float*)d_in[0];
  const int* caps   = (const int*)d_in[1];
  const int* clen   = (const int*)d_in[2];
  const float* embW = (const float*)d_in[3];
  const float* Wih  = (const float*)d_in[4];
  const float* Whh  = (const float*)d_in[5];
  const float* bih  = (const float*)d_in[6];
  const float* bhh  = (const float*)d_in[7];
  const float* linW = (const float*)d_in[8];
  const float* linb = (const float*)d_in[9];

  float* out_pred = (float*)d_out;                       // [64][51][32000]
  float* out_caps = out_pred + (size_t)64 * 51 * 32000;  // [64][52]
  float* out_dl   = out_caps + 64 * 52;                  // [64]
  float* out_si   = out_dl + 64;                         // [64]

  char* p = (char*)d_ws;
  auto alloc = [&](size_t bytes) {
    char* r = p;
    p += (bytes + 255) & ~(size_t)255;
    return r;
  };
  int* ws_caps = (int*)alloc(64 * 52 * sizeof(int));
  int* ws_dl   = (int*)alloc(64 * sizeof(int));
  int* bar     = (int*)alloc(256);
  unsigned short* A_emb = (unsigned short*)alloc((size_t)3328 * 512 * 2);  // padded M
  unsigned short* WihB  = (unsigned short*)alloc((size_t)2048 * 512 * 2);
  unsigned short* WhhB  = (unsigned short*)alloc((size_t)2048 * 512 * 2);
  unsigned short* linWB = (unsigned short*)alloc((size_t)32000 * 512 * 2);
  float* Xpre = (float*)alloc((size_t)3264 * 2048 * sizeof(float));
  unsigned short* Hall = (unsigned short*)alloc((size_t)3328 * 512 * 2);   // padded M
  unsigned short* hc0  = (unsigned short*)alloc((size_t)64 * 512 * 2);
  unsigned short* hc1  = (unsigned short*)alloc((size_t)64 * 512 * 2);

  k_sort<<<1, 256, 0, stream>>>(img, caps, clen, out_caps, out_dl, out_si,
                                ws_caps, ws_dl, hc0, bar);
  k_cast<<<(2048 * 512 / 4 + 255) / 256, 256, 0, stream>>>(Wih, WihB, 2048 * 512 / 4);
  k_cast<<<(2048 * 512 / 4 + 255) / 256, 256, 0, stream>>>(Whh, WhhB, 2048 * 512 / 4);
  k_cast<<<(32000 * 512 / 4 + 255) / 256, 256, 0, stream>>>(linW, linWB, 32000 * 512 / 4);
  k_gather<<<3264, 256, 0, stream>>>(embW, ws_caps, A_emb);

  // Xpre = emb @ W_ih^T + b_ih + b_hh : M=3264, N=2048 -> 26x16 = 416 tiles
  {
    int total = 26 * 16, per = (total + 7) / 8;
    gemm_bt<0><<<per * 8, 256, 0, stream>>>(A_emb, WihB, Xpre, 3264, 2048, bih, bhh, nullptr, per);
  }

  // all 51 recurrent steps in one persistent launch
  lstm_persist<<<32, 512, 0, stream>>>(hc0, hc1, WhhB, Xpre, Hall, bar);

  // predictions = mask(H @ lin_W^T + lin_b) : M=3264, N=32000 -> 26x250 = 6500 tiles
  {
    int total = 26 * 250, per = (total + 7) / 8;   // 813 -> grid 6504
    gemm_bt<1><<<per * 8, 256, 0, stream>>>(Hall, linWB, out_pred, 3264, 32000, linb, nullptr, ws_dl, per);
  }
}

// Round 5
// 939.198 us; speedup vs baseline: 1.6890x; 1.6890x over previous
//
#include <hip/hip_runtime.h>
#include <cstdint>
#include <cstddef>

// ---------------- types ----------------
typedef __attribute__((ext_vector_type(8))) __bf16 bf16x8;   // MFMA A/B frag (4 VGPRs)
typedef __attribute__((ext_vector_type(4))) float  f32x4;    // MFMA C/D frag

__device__ __forceinline__ unsigned short f2bf(float f) {
  unsigned u = __float_as_uint(f);
  u += 0x7FFFu + ((u >> 16) & 1u);   // round-to-nearest-even
  return (unsigned short)(u >> 16);
}

// async global->LDS, 16B per lane; LDS dest is wave-uniform base + lane*16
__device__ __forceinline__ void gl_lds16(const void* g, void* l) {
  __builtin_amdgcn_global_load_lds(
      (const __attribute__((address_space(1))) char*)g,
      (__attribute__((address_space(3))) char*)l, 16, 0, 0);
}

__device__ __forceinline__ float sigm(float x) { return 1.f / (1.f + __expf(-x)); }
__device__ __forceinline__ float ftanh(float x) {
  x = fminf(15.f, fmaxf(-15.f, x));
  float e = __expf(2.f * x);
  return (e - 1.f) / (e + 1.f);
}

// ---------------- sort + meta outputs + gathers (1 block) ----------------
__global__ __launch_bounds__(256) void k_sort(
    const float* __restrict__ img, const int* __restrict__ caps,
    const int* __restrict__ clen,
    float* __restrict__ out_caps, float* __restrict__ out_dl, float* __restrict__ out_si,
    int* __restrict__ ws_caps, int* __restrict__ ws_dl,
    unsigned short* __restrict__ h0,
    int* __restrict__ bar)
{
  __shared__ int len_s[64], si_s[64], dl_s[64];
  const int tid = threadIdx.x;
  for (int i = tid; i < 512; i += 256) bar[i] = 0;   // clear flag array
  if (tid < 64) len_s[tid] = clen[tid];
  __syncthreads();
  if (tid < 64) {
    int li = len_s[tid], r = 0;
    for (int j = 0; j < 64; j++) {
      int lj = len_s[j];
      if (lj > li || (lj == li && j < tid)) r++;   // stable descending rank
    }
    si_s[r] = tid;
    dl_s[r] = li - 1;
  }
  __syncthreads();
  if (tid < 64) {
    out_si[tid] = (float)si_s[tid];
    out_dl[tid] = (float)dl_s[tid];
    ws_dl[tid] = dl_s[tid];
  }
  for (int i = tid; i < 64 * 52; i += 256) {
    int p = i / 52, t = i - p * 52;
    int v = caps[si_s[p] * 52 + t];
    out_caps[i] = (float)v;
    ws_caps[i] = v;
  }
  for (int i = tid; i < 64 * 512; i += 256) {
    int b = i >> 9, k = i & 511;
    h0[i] = f2bf(img[si_s[b] * 512 + k]);
  }
}

// ---------------- fp32 -> bf16 cast (vectorized x4) ----------------
__global__ void k_cast(const float* __restrict__ s, unsigned short* __restrict__ d, int n4) {
  int i = blockIdx.x * blockDim.x + threadIdx.x;
  if (i < n4) {
    float4 v = ((const float4*)s)[i];
    ushort4 o;
    o.x = f2bf(v.x); o.y = f2bf(v.y); o.z = f2bf(v.z); o.w = f2bf(v.w);
    ((ushort4*)d)[i] = o;
  }
}

// ---------------- embedding gather -> bf16 A matrix [3264][512] ----------------
__global__ __launch_bounds__(256) void k_gather(
    const float* __restrict__ embW, const int* __restrict__ ws_caps,
    unsigned short* __restrict__ A)
{
  int m = blockIdx.x;                 // 0..3263, m = b*51 + t
  int b = m / 51, t = m - b * 51;
  int tok = ws_caps[b * 52 + t];
  const float* src = embW + (size_t)tok * 512;
  unsigned short* dst = A + (size_t)m * 512;
  for (int k = threadIdx.x; k < 512; k += 256) dst[k] = f2bf(src[k]);
}

// ---------------- 128x128 MFMA GEMM, BK=64, XOR-swizzled LDS ----------------
// C = A(MxK) @ Bt(NxK)^T, K=512
// EPI 0: out = acc + bias1[col] + bias2[col]          (Xpre)
// EPI 1: out = (t < dl[b]) ? acc + bias1[col] : 0     (predictions; row = b*51+t)
template <int EPI>
__global__ __launch_bounds__(256) void gemm_bt(
    const unsigned short* __restrict__ A, const unsigned short* __restrict__ Bt,
    float* __restrict__ out, int M, int N,
    const float* __restrict__ bias1, const float* __restrict__ bias2,
    const int* __restrict__ dl, int per_xcd)
{
  constexpr int K = 512;
  constexpr int BK = 64;
  __shared__ unsigned short smA[128 * BK];   // 16 KB
  __shared__ unsigned short smB[128 * BK];   // 16 KB
  const int mtiles = (M + 127) >> 7;
  const int total = mtiles * ((N + 127) >> 7);
  int tile = (blockIdx.x & 7) * per_xcd + (blockIdx.x >> 3);
  if (tile >= total) return;
  const int bm = tile % mtiles;
  const int bn = tile / mtiles;
  const int wave = threadIdx.x >> 6;
  const int lane = threadIdx.x & 63;
  const int crow = lane >> 3;                // row within 8-row 1KB chunk
  const int cu   = lane & 7;                 // 16B unit within 128B row
  const int wr = (wave >> 1) * 64;
  const int wc = (wave & 1) * 64;
  const int rsel = lane & 15;
  const int ko = (lane >> 4) * 8;            // 0,8,16,24
  const unsigned short* Ab = A + (size_t)bm * 128 * K;
  const unsigned short* Bb = Bt + (size_t)bn * 128 * K;
  f32x4 acc[4][4] = {};
  for (int k0 = 0; k0 < K; k0 += BK) {
#pragma unroll
    for (int cc = 0; cc < 4; cc++) {
      int chunk = wave * 4 + cc;
      int row = chunk * 8 + crow;
      int gu = cu ^ (row & 7);               // global 16B-unit (swizzle source)
      gl_lds16(Ab + (size_t)row * K + k0 + gu * 8, (char*)smA + chunk * 1024);
      gl_lds16(Bb + (size_t)row * K + k0 + gu * 8, (char*)smB + chunk * 1024);
    }
    __syncthreads();
    bf16x8 af[2][4], bfr[2][4];
#pragma unroll
    for (int kh = 0; kh < 2; kh++) {
      int u = kh * 4 + (ko >> 3);            // 16B unit index 0..7
#pragma unroll
      for (int mt = 0; mt < 4; mt++) {
        int row = wr + mt * 16 + rsel;
        af[kh][mt] = *(const bf16x8*)&smA[row * BK + ((u ^ (row & 7)) << 3)];
      }
#pragma unroll
      for (int nt = 0; nt < 4; nt++) {
        int row = wc + nt * 16 + rsel;
        bfr[kh][nt] = *(const bf16x8*)&smB[row * BK + ((u ^ (row & 7)) << 3)];
      }
    }
#pragma unroll
    for (int kh = 0; kh < 2; kh++)
#pragma unroll
      for (int mt = 0; mt < 4; mt++)
#pragma unroll
        for (int nt = 0; nt < 4; nt++)
          acc[mt][nt] = __builtin_amdgcn_mfma_f32_16x16x32_bf16(af[kh][mt], bfr[kh][nt], acc[mt][nt], 0, 0, 0);
    __syncthreads();
  }
  // epilogue: C mapping col=lane&15, row=(lane>>4)*4+reg
#pragma unroll
  for (int mt = 0; mt < 4; mt++) {
#pragma unroll
    for (int nt = 0; nt < 4; nt++) {
      int row0 = bm * 128 + wr + mt * 16 + (lane >> 4) * 4;
      int col = bn * 128 + wc + nt * 16 + (lane & 15);
      float b1 = bias1[col];
#pragma unroll
      for (int r = 0; r < 4; r++) {
        int row = row0 + r;
        if (row < M) {
          float v = acc[mt][nt][r];
          if (EPI == 0) {
            out[(size_t)row * N + col] = v + b1 + bias2[col];
          } else {
            int b = row / 51;
            int t = row - b * 51;
            out[(size_t)row * N + col] = (t < dl[b]) ? (v + b1) : 0.f;
          }
        }
      }
    }
  }
}

// ---------------- persistent fused LSTM: all 51 steps in one launch ----------
// 32 blocks x 512 threads; block g owns h-columns [16g,16g+16) for all 4 gates.
// Whh panel in registers (wf[16], AGPR-resident). NO cache-maintenance fences:
//  - h history is WRITE-ONCE: step t's h goes to Hall[:,t] via agent-scope
//    bypass stores (land at the IC coherence point; round-3-proven visible).
//  - step t reads Hall[:,t-1] via global_load_lds on the normal cached path.
//    Those addresses were never in any L1/L2 before their write (write-once
//    within this dispatch; dispatch-boundary invalidation covers prior
//    launches), so a cached-path miss is guaranteed to fetch fresh IC data.
//  - LDS staging (64KB) has zero VGPR cost -> all 8 requests/thread in
//    flight, one vmcnt drain at the barrier (fixes r2/r3's load->MFMA
//    serialization, which VGPR_Count=60 exposed).
//  - grid barrier: per-block flag array (64B stride), wave 0 polls all 32
//    flags with 32 lanes in parallel (no serialized atomicAdd chain).
// Ordering: __syncthreads' barrier-entry s_waitcnt vmcnt(0) drains each
// wave's bypass stores BEFORE wave 0 publishes flags[g]=t+1.
__global__ __launch_bounds__(512, 2) void lstm_persist(
    const unsigned short* __restrict__ h0,     // [64][512] bf16 initial h
    const unsigned short* __restrict__ Whh,    // [2048][512] bf16
    const float* __restrict__ Xpre,            // [3264][2048] fp32
    unsigned short* __restrict__ Hall,         // [3328][512] bf16, write-once h history
    int* __restrict__ bar)                     // flags: bar[g*16], g=0..31
{
  __shared__ unsigned short smH[64 * 512];     // 64 KB staged h(t-1), XOR-swizzled
  __shared__ float smG[4][64][20];             // 20.5 KB gate exchange (pad 20)
  const int g = blockIdx.x;                    // 0..31
  const int tid = threadIdx.x;
  const int wave = tid >> 6;
  const int lane = tid & 63;
  const int wm = wave >> 2;                    // 0..1 (batch half)
  const int wn = wave & 3;                     // 0..3 (gate)
  const int rsel = lane & 15;
  const int quad = lane >> 4;

  // one-time: this wave's Whh panel -> registers (AGPR-resident).
  // B-frag ks: lane holds Whh[row = wn*512 + g*16 + rsel][ks*32 + quad*8 ..+8)
  bf16x8 wf[16];
  {
    const unsigned short* wsrc =
        Whh + (size_t)(wn * 512 + g * 16 + rsel) * 512 + quad * 8;
#pragma unroll
    for (int ks = 0; ks < 16; ks++)
      wf[ks] = *(const bf16x8*)(wsrc + ks * 32);
  }

  // per-thread element ownership: e0=(b0,jj), e1=(b1,jj)
  const int jj = tid & 15;
  const int b0 = tid >> 4;        // 0..31
  const int b1 = b0 + 32;         // 32..63
  float c0 = 0.f, c1 = 0.f;       // cell state in registers

  const float* x0base = Xpre + (size_t)b0 * 51 * 2048 + g * 16 + jj;
  const float* x1base = Xpre + (size_t)b1 * 51 * 2048 + g * 16 + jj;
  float xp0[4], xp1[4];
#pragma unroll
  for (int q = 0; q < 4; q++) { xp0[q] = x0base[q * 512]; xp1[q] = x1base[q * 512]; }

  for (int t = 0; t < 51; t++) {
    // ---- stage h(t-1) -> smH: wave w stages rows [8w, 8w+8), 1KB each ----
    // LDS row r is XOR-swizzled: physical 16B-unit = logical ^ (r & 15);
    // achieved by pre-swizzling the per-lane GLOBAL source (LDS dest linear).
    {
      const unsigned short* hbase = (t == 0) ? h0 : Hall + (size_t)(t - 1) * 512;
      const size_t rstride = (t == 0) ? 512 : (size_t)51 * 512;   // batch stride
#pragma unroll
      for (int i = 0; i < 8; i++) {
        int r = wave * 8 + i;
        gl_lds16(hbase + (size_t)r * rstride + ((lane ^ (r & 15)) << 3),
                 (char*)smH + (r << 10));
      }
    }
    __syncthreads();   // drains gl_lds (vmcnt 0) + joins

    // ---- GEMM: out[64 batch][64 gate-cols], K=512, B from registers ----
    f32x4 acc0 = {}, acc1 = {};
#pragma unroll
    for (int ks = 0; ks < 16; ks++) {
      int pu = (ks * 4 + quad) ^ rsel;       // swizzled 16B unit
      bf16x8 a0 = *(const bf16x8*)&smH[((wm * 32 + rsel) << 9) + (pu << 3)];
      bf16x8 a1 = *(const bf16x8*)&smH[((wm * 32 + 16 + rsel) << 9) + (pu << 3)];
      acc0 = __builtin_amdgcn_mfma_f32_16x16x32_bf16(a0, wf[ks], acc0, 0, 0, 0);
      acc1 = __builtin_amdgcn_mfma_f32_16x16x32_bf16(a1, wf[ks], acc1, 0, 0, 0);
    }

    // ---- exchange through LDS: col=lane&15 -> gate-col, row=quad*4+r -> batch
#pragma unroll
    for (int r = 0; r < 4; r++) smG[wn][wm * 32 + quad * 4 + r][rsel] = acc0[r];
#pragma unroll
    for (int r = 0; r < 4; r++) smG[wn][wm * 32 + 16 + quad * 4 + r][rsel] = acc1[r];
    __syncthreads();

    // ---- fused LSTM elementwise (2 elements/thread), c in registers ----
    {
      float iv = smG[0][b0][jj] + xp0[0];
      float fv = smG[1][b0][jj] + xp0[1];
      float gv = smG[2][b0][jj] + xp0[2];
      float ov = smG[3][b0][jj] + xp0[3];
      c0 = sigm(fv) * c0 + sigm(iv) * ftanh(gv);
      float hn = sigm(ov) * ftanh(c0);
      __hip_atomic_store(&Hall[(size_t)(b0 * 51 + t) * 512 + g * 16 + jj], f2bf(hn),
                         __ATOMIC_RELAXED, __HIP_MEMORY_SCOPE_AGENT);
    }
    {
      float iv = smG[0][b1][jj] + xp1[0];
      float fv = smG[1][b1][jj] + xp1[1];
      float gv = smG[2][b1][jj] + xp1[2];
      float ov = smG[3][b1][jj] + xp1[3];
      c1 = sigm(fv) * c1 + sigm(iv) * ftanh(gv);
      float hn = sigm(ov) * ftanh(c1);
      __hip_atomic_store(&Hall[(size_t)(b1 * 51 + t) * 512 + g * 16 + jj], f2bf(hn),
                         __ATOMIC_RELAXED, __HIP_MEMORY_SCOPE_AGENT);
    }

    // ---- flag-array grid barrier (none after last step) ----
    if (t != 50) {
      // prefetch next step's Xpre (overlaps the barrier wait)
#pragma unroll
      for (int q = 0; q < 4; q++) {
        xp0[q] = x0base[(size_t)(t + 1) * 2048 + q * 512];
        xp1[q] = x1base[(size_t)(t + 1) * 2048 + q * 512];
      }
      __syncthreads();   // vmcnt(0): this block's Hall stores are at IC; smG closed
      if (wave == 0) {
        if (lane == 0)
          __hip_atomic_store(&bar[g * 16], t + 1, __ATOMIC_RELAXED, __HIP_MEMORY_SCOPE_AGENT);
        for (;;) {
          int v = (lane < 32)
              ? __hip_atomic_load(&bar[lane * 16], __ATOMIC_RELAXED, __HIP_MEMORY_SCOPE_AGENT)
              : 0x7fffffff;
          if (__all(v >= t + 1)) break;
          __builtin_amdgcn_s_sleep(1);
        }
      }
      __syncthreads();
    }
  }
}

// ---------------- launch ----------------
extern "C" void kernel_launch(void* const* d_in, const int* in_sizes, int n_in,
                              void* d_out, int out_size, void* d_ws, size_t ws_size,
                              hipStream_t stream)
{
  const float* img  = (const float*)d_in[0];
  const int* caps   = (const int*)d_in[1];
  const int* clen   = (const int*)d_in[2];
  const float* embW = (const float*)d_in[3];
  const float* Wih  = (const float*)d_in[4];
  const float* Whh  = (const float*)d_in[5];
  const float* bih  = (const float*)d_in[6];
  const float* bhh  = (const float*)d_in[7];
  const float* linW = (const float*)d_in[8];
  const float* linb = (const float*)d_in[9];

  float* out_pred = (float*)d_out;                       // [64][51][32000]
  float* out_caps = out_pred + (size_t)64 * 51 * 32000;  // [64][52]
  float* out_dl   = out_caps + 64 * 52;                  // [64]
  float* out_si   = out_dl + 64;                         // [64]

  char* p = (char*)d_ws;
  auto alloc = [&](size_t bytes) {
    char* r = p;
    p += (bytes + 255) & ~(size_t)255;
    return r;
  };
  int* ws_caps = (int*)alloc(64 * 52 * sizeof(int));
  int* ws_dl   = (int*)alloc(64 * sizeof(int));
  int* bar     = (int*)alloc(2048);
  unsigned short* A_emb = (unsigned short*)alloc((size_t)3328 * 512 * 2);  // padded M
  unsigned short* WihB  = (unsigned short*)alloc((size_t)2048 * 512 * 2);
  unsigned short* WhhB  = (unsigned short*)alloc((size_t)2048 * 512 * 2);
  unsigned short* linWB = (unsigned short*)alloc((size_t)32000 * 512 * 2);
  float* Xpre = (float*)alloc((size_t)3264 * 2048 * sizeof(float));
  unsigned short* Hall = (unsigned short*)alloc((size_t)3328 * 512 * 2);   // padded M
  unsigned short* hc0  = (unsigned short*)alloc((size_t)64 * 512 * 2);     // h0

  k_sort<<<1, 256, 0, stream>>>(img, caps, clen, out_caps, out_dl, out_si,
                                ws_caps, ws_dl, hc0, bar);
  k_cast<<<(2048 * 512 / 4 + 255) / 256, 256, 0, stream>>>(Wih, WihB, 2048 * 512 / 4);
  k_cast<<<(2048 * 512 / 4 + 255) / 256, 256, 0, stream>>>(Whh, WhhB, 2048 * 512 / 4);
  k_cast<<<(32000 * 512 / 4 + 255) / 256, 256, 0, stream>>>(linW, linWB, 32000 * 512 / 4);
  k_gather<<<3264, 256, 0, stream>>>(embW, ws_caps, A_emb);

  // Xpre = emb @ W_ih^T + b_ih + b_hh : M=3264, N=2048 -> 26x16 = 416 tiles
  {
    int total = 26 * 16, per = (total + 7) / 8;
    gemm_bt<0><<<per * 8, 256, 0, stream>>>(A_emb, WihB, Xpre, 3264, 2048, bih, bhh, nullptr, per);
  }

  // all 51 recurrent steps in one persistent launch
  lstm_persist<<<32, 512, 0, stream>>>(hc0, WhhB, Xpre, Hall, bar);

  // predictions = mask(H @ lin_W^T + lin_b) : M=3264, N=32000 -> 26x250 = 6500 tiles
  {
    int total = 26 * 250, per = (total + 7) / 8;   // 813 -> grid 6504
    gemm_bt<1><<<per * 8, 256, 0, stream>>>(Hall, linWB, out_pred, 3264, 32000, linb, nullptr, ws_dl, per);
  }
}